// Round 1
// baseline (795.013 us; speedup 1.0000x reference)
//
#include <hip/hip_runtime.h>

#define NB 16
#define SEQ 4096
#define DIMC 1024
#define NH 16
#define DH 64
#define SCHUNK 32           // chunks per batch
#define ROWS_PER_CHUNK 128  // SEQ / SCHUNK
#define RBLK 16             // rows staged in LDS per block-iter

// ws layout (floats):
// wtil : [16][16][1024]      off 0        (262144)
// y_ws : [16][32][16][1024]  off 262144   (8388608)
// m_ws : [16][32][16]        off 8650752  (8192)
// l_ws : [16][32][16]        off 8658944  (8192)
// ho   : [16][1024]          off 8667136  (16384)
// total 8683520 floats = 33.1 MB

// ---------------- K1: q = x0 @ Wq ; wtil[b,h,c] = 0.125 * sum_d Wk[c,h*64+d]*q[d]
__global__ __launch_bounds__(256) void k_prep(const float* __restrict__ x,
                                              const float* __restrict__ Wq,
                                              const float* __restrict__ Wk,
                                              float* __restrict__ wtil) {
  const int h = blockIdx.x, b = blockIdx.y, t = threadIdx.x;
  const int d = t & 63, g = t >> 6;
  const float* x0 = x + (size_t)b * SEQ * DIMC;  // token 0 of batch b
  const int col = h * DH + d;
  float qp = 0.f;
  #pragma unroll 4
  for (int c = g * 256; c < g * 256 + 256; ++c)
    qp = fmaf(x0[c], Wq[(size_t)c * DIMC + col], qp);
  __shared__ float qred[4][64];
  __shared__ float qs[64];
  qred[g][d] = qp;
  __syncthreads();
  if (t < 64) qs[t] = qred[0][t] + qred[1][t] + qred[2][t] + qred[3][t];
  __syncthreads();
  float* wt = wtil + ((size_t)b * NH + h) * DIMC;
  for (int c = t; c < DIMC; c += 256) {
    const float* wkr = Wk + (size_t)c * DIMC + h * DH;
    float s = 0.f;
    #pragma unroll
    for (int dd = 0; dd < DH; ++dd) s = fmaf(wkr[dd], qs[dd], s);
    wt[c] = s * 0.125f;  // scale = DH^-0.5
  }
}

// ---------------- K2: fused logits + online softmax + y = p @ x  (per (b, chunk))
__global__ __launch_bounds__(256) void k_attn(const float* __restrict__ x,
                                              const float* __restrict__ wtil,
                                              float* __restrict__ y_ws,
                                              float* __restrict__ m_ws,
                                              float* __restrict__ l_ws) {
  const int s = blockIdx.x, b = blockIdx.y, t = threadIdx.x;
  const int h = t >> 4, sl = t & 15;  // phase-1 mapping
  // padded x rows: 16 slices of 64 floats, slice stride 68 floats (17 float4)
  __shared__ float xl[RBLK * 1088];
  __shared__ __align__(16) float pl[RBLK][16];
  __shared__ float mst[16], lst[16], alf[16];
  float4* const xl4 = (float4*)xl;

  // per-thread wtil fragment: 64 floats of head h, cols sl*64 .. sl*64+63
  float4 wreg[16];
  {
    const float4* wp4 = (const float4*)(wtil + ((size_t)b * NH + h) * DIMC + sl * 64);
    #pragma unroll
    for (int i = 0; i < 16; ++i) wreg[i] = wp4[i];
  }
  float4 acc[16];
  #pragma unroll
  for (int hh = 0; hh < 16; ++hh) acc[hh] = make_float4(0.f, 0.f, 0.f, 0.f);
  if (t < 16) { mst[t] = -3.0e38f; lst[t] = 0.f; }

  const float4* src4 = (const float4*)(x + ((size_t)b * SEQ + (size_t)s * ROWS_PER_CHUNK) * DIMC);
  const int sliceW = t >> 4, posW = t & 15;  // staging / phase-2 float4 coords

  for (int r0 = 0; r0 < ROWS_PER_CHUNK; r0 += RBLK) {
    __syncthreads();  // previous iter's readers done before overwrite
    #pragma unroll
    for (int i = 0; i < RBLK; ++i)
      xl4[i * 272 + sliceW * 17 + posW] = src4[(size_t)(r0 + i) * 256 + t];
    __syncthreads();

    // phase 1: logits for RBLK rows, all 16 heads
    for (int r = 0; r < RBLK; ++r) {
      const float4* xr = xl4 + r * 272 + sl * 17;
      float p = 0.f;
      #pragma unroll
      for (int i = 0; i < 16; ++i) {
        float4 xv = xr[i];
        float4 wv = wreg[i];
        p = fmaf(xv.x, wv.x, p); p = fmaf(xv.y, wv.y, p);
        p = fmaf(xv.z, wv.z, p); p = fmaf(xv.w, wv.w, p);
      }
      p += __shfl_xor(p, 1); p += __shfl_xor(p, 2);
      p += __shfl_xor(p, 4); p += __shfl_xor(p, 8);
      if (sl == 0) pl[r][h] = p;
    }
    __syncthreads();

    // stage A: per-head chunk softmax bookkeeping (16 threads)
    if (t < 16) {
      float mo = mst[t], lo = lst[t];
      float mc = -3.0e38f;
      #pragma unroll
      for (int r = 0; r < RBLK; ++r) mc = fmaxf(mc, pl[r][t]);
      float mn = fmaxf(mo, mc);
      float a = __expf(mo - mn);
      float lsum = 0.f;
      #pragma unroll
      for (int r = 0; r < RBLK; ++r) {
        float e = __expf(pl[r][t] - mn);
        pl[r][t] = e;
        lsum += e;
      }
      mst[t] = mn;
      lst[t] = lo * a + lsum;
      alf[t] = a;
    }
    __syncthreads();

    // phase 2: acc[h] = acc[h]*alpha[h] + sum_r p[r][h] * x[r, c-quad]
    #pragma unroll
    for (int hh = 0; hh < 16; ++hh) {
      float a = alf[hh];
      acc[hh].x *= a; acc[hh].y *= a; acc[hh].z *= a; acc[hh].w *= a;
    }
    for (int r = 0; r < RBLK; ++r) {
      float4 xv = xl4[r * 272 + sliceW * 17 + posW];
      #pragma unroll
      for (int hh = 0; hh < 16; ++hh) {
        float p = pl[r][hh];
        acc[hh].x = fmaf(p, xv.x, acc[hh].x);
        acc[hh].y = fmaf(p, xv.y, acc[hh].y);
        acc[hh].z = fmaf(p, xv.z, acc[hh].z);
        acc[hh].w = fmaf(p, xv.w, acc[hh].w);
      }
    }
  }

  // epilogue: partial y (unnormalized), m, l
  float4* ypb = (float4*)(y_ws + (((size_t)b * SCHUNK + s) * NH) * DIMC);
  #pragma unroll
  for (int hh = 0; hh < 16; ++hh) ypb[hh * 256 + t] = acc[hh];
  if (t < 16) {
    m_ws[((size_t)b * SCHUNK + s) * NH + t] = mst[t];
    l_ws[((size_t)b * SCHUNK + s) * NH + t] = lst[t];
  }
}

// ---------------- K3: combine chunk partials, then ho[b, h*64+d] = (y/L) . Wv[:, h*64+d]
__global__ __launch_bounds__(256) void k_comb(const float* __restrict__ y_ws,
                                              const float* __restrict__ m_ws,
                                              const float* __restrict__ l_ws,
                                              const float* __restrict__ Wv,
                                              float* __restrict__ ho) {
  const int h = blockIdx.x, b = blockIdx.y, t = threadIdx.x;
  __shared__ float esc[32];
  __shared__ float ylds[1024];
  __shared__ float red[256];
  if (t < 32) {
    float m = m_ws[((size_t)b * SCHUNK + t) * NH + h];
    float M = m;
    #pragma unroll
    for (int o = 1; o < 32; o <<= 1) M = fmaxf(M, __shfl_xor(M, o));
    float le = l_ws[((size_t)b * SCHUNK + t) * NH + h] * __expf(m - M);
    float L = le;
    #pragma unroll
    for (int o = 1; o < 32; o <<= 1) L += __shfl_xor(L, o);
    esc[t] = __expf(m - M) / L;
  }
  __syncthreads();
  for (int c = t; c < 1024; c += 256) {
    float a = 0.f;
    #pragma unroll
    for (int s = 0; s < SCHUNK; ++s)
      a = fmaf(y_ws[(((size_t)b * SCHUNK + s) * NH + h) * DIMC + c], esc[s], a);
    ylds[c] = a;
  }
  __syncthreads();
  const int d = t & 63, g = t >> 6;
  float part = 0.f;
  const float* wv = Wv + h * DH + d;
  for (int c = g * 256; c < g * 256 + 256; ++c)
    part = fmaf(ylds[c], wv[(size_t)c * DIMC], part);
  red[t] = part;
  __syncthreads();
  if (t < 64) ho[(size_t)b * DIMC + h * DH + d] = red[d] + red[64 + d] + red[128 + d] + red[192 + d];
}

// ---------------- K4: out[b,:] = ho[b,:] @ Wp + bp
__global__ __launch_bounds__(256) void k_out(const float* __restrict__ ho,
                                             const float* __restrict__ Wp,
                                             const float* __restrict__ bp,
                                             float* __restrict__ out) {
  const int b = blockIdx.x, jb = blockIdx.y, t = threadIdx.x;
  __shared__ float hs[1024];
  for (int i = t; i < 1024; i += 256) hs[i] = ho[(size_t)b * DIMC + i];
  __syncthreads();
  const int j = jb * 256 + t;
  float a = bp[j];
  #pragma unroll 8
  for (int i = 0; i < 1024; ++i) a = fmaf(hs[i], Wp[(size_t)i * DIMC + j], a);
  out[(size_t)b * DIMC + j] = a;
}

extern "C" void kernel_launch(void* const* d_in, const int* in_sizes, int n_in,
                              void* d_out, int out_size, void* d_ws, size_t ws_size,
                              hipStream_t stream) {
  const float* x  = (const float*)d_in[0];
  const float* Wq = (const float*)d_in[1];
  const float* Wk = (const float*)d_in[2];
  const float* Wv = (const float*)d_in[3];
  const float* Wp = (const float*)d_in[4];
  const float* bp = (const float*)d_in[5];
  float* out = (float*)d_out;
  float* ws = (float*)d_ws;

  float* wtil = ws;
  float* y_ws = ws + 262144;
  float* m_ws = y_ws + 8388608;
  float* l_ws = m_ws + 8192;
  float* ho   = l_ws + 8192;

  k_prep<<<dim3(NH, NB), 256, 0, stream>>>(x, Wq, Wk, wtil);
  k_attn<<<dim3(SCHUNK, NB), 256, 0, stream>>>(x, wtil, y_ws, m_ws, l_ws);
  k_comb<<<dim3(NH, NB), 256, 0, stream>>>(y_ws, m_ws, l_ws, Wv, ho);
  k_out<<<dim3(NB, 4), 256, 0, stream>>>(ho, Wp, bp, out);
}